// Round 1
// baseline (89.127 us; speedup 1.0000x reference)
//
#include <hip/hip_runtime.h>
#include <stdint.h>

#define NB    64       // batch
#define KMAX  16
#define VV    32000    // vocab
#define DVV   10
#define HH    4096
#define NROWS (NB*KMAX)
#define EPSF  1e-8f

// ---------------- Threefry-2x32 (exact JAX reference implementation) ----------------
__device__ __forceinline__ uint32_t rotl32(uint32_t v, int r) { return (v << r) | (v >> (32 - r)); }

__device__ __forceinline__ void tf2x32(uint32_t k0, uint32_t k1, uint32_t c0, uint32_t c1,
                                       uint32_t& o0, uint32_t& o1) {
    uint32_t ks2 = k0 ^ k1 ^ 0x1BD11BDAu;
    uint32_t x0 = c0 + k0, x1 = c1 + k1;
    const int RA[4] = {13, 15, 26, 6};
    const int RB[4] = {17, 29, 16, 24};
#pragma unroll
    for (int i = 0; i < 4; ++i) { x0 += x1; x1 = rotl32(x1, RA[i]); x1 ^= x0; }
    x0 += k1; x1 += ks2 + 1u;
#pragma unroll
    for (int i = 0; i < 4; ++i) { x0 += x1; x1 = rotl32(x1, RB[i]); x1 ^= x0; }
    x0 += ks2; x1 += k0 + 2u;
#pragma unroll
    for (int i = 0; i < 4; ++i) { x0 += x1; x1 = rotl32(x1, RA[i]); x1 ^= x0; }
    x0 += k0; x1 += k1 + 3u;
#pragma unroll
    for (int i = 0; i < 4; ++i) { x0 += x1; x1 = rotl32(x1, RB[i]); x1 ^= x0; }
    x0 += k1; x1 += ks2 + 4u;
#pragma unroll
    for (int i = 0; i < 4; ++i) { x0 += x1; x1 = rotl32(x1, RA[i]); x1 ^= x0; }
    x0 += ks2; x1 += k0 + 5u;
    o0 = x0; o1 = x1;
}

__device__ __forceinline__ float bits_to_u01(uint32_t bits) {
    uint32_t fb = (bits >> 9) | 0x3F800000u;
    return __uint_as_float(fb) - 1.0f;
}

// ------------- setup: reproduce JAX randoms, build per-row descriptors -------------
// src_arr[row] >= 0 : copy from row (b, src) ;  src_arr[row] < 0 : warp with itau_arr[row]
__global__ void setup_kernel(const int* __restrict__ k_vals,
                             int* __restrict__ src_arr, float* __restrict__ itau_arr) {
    int b = threadIdx.x;
    if (b >= NB) return;

    // split(key(0), 3): counts=[0..5]; x0=[0,1,2], x1=[3,4,5]
    // out = [a0,a1,a2,b0,b1,b2] -> reshape(3,2): kdec=(a0,a1), kperm=(a2,b0), ktau=(b1,b2)
    uint32_t a0, b0, a1, b1, a2, b2;
    tf2x32(0u, 0u, 0u, 3u, a0, b0);
    tf2x32(0u, 0u, 1u, 4u, a1, b1);
    tf2x32(0u, 0u, 2u, 5u, a2, b2);
    uint32_t kdec0 = a0, kdec1 = a1;
    uint32_t kperm0 = a2, kperm1 = b0;
    uint32_t ktau0 = b1, ktau1 = b2;

    // u_dec: shape (64,), counts split as [0..31],[32..63]
    uint32_t y0, y1, bits;
    if (b < 32) { tf2x32(kdec0, kdec1, (uint32_t)b, (uint32_t)(b + 32), y0, y1); bits = y0; }
    else        { tf2x32(kdec0, kdec1, (uint32_t)(b - 32), (uint32_t)b, y0, y1); bits = y1; }
    float u_dec = bits_to_u01(bits);   // minval=0: max(0,u) is identity

    int k = k_vals[b];
    float prob = (k >= 2) ? 0.5f : 0.0f;
    bool do_permute = (k > 1) && (u_dec < prob);

    // u_perm, tau: shape sizes 1024, counts split as [0..511],[512..1023], row-major [b][s]
    float uperm[KMAX], tauv[KMAX];
#pragma unroll
    for (int s = 0; s < KMAX; ++s) {
        int j = b * KMAX + s;
        uint32_t pb, tb;
        if (j < 512) { tf2x32(kperm0, kperm1, (uint32_t)j, (uint32_t)(j + 512), y0, y1); pb = y0; }
        else         { tf2x32(kperm0, kperm1, (uint32_t)(j - 512), (uint32_t)j, y0, y1); pb = y1; }
        uperm[s] = bits_to_u01(pb);
        if (j < 512) { tf2x32(ktau0, ktau1, (uint32_t)j, (uint32_t)(j + 512), y0, y1); tb = y0; }
        else         { tf2x32(ktau0, ktau1, (uint32_t)(j - 512), (uint32_t)j, y0, y1); tb = y1; }
        float u = bits_to_u01(tb);
        float t = u * (1.6f - 0.7f) + 0.7f;
        tauv[s] = fmaxf(0.7f, t);
    }

    // stable argsort of (active ? uperm : +inf)
    float keyv[KMAX];
    int idx[KMAX];
    for (int s = 0; s < KMAX; ++s) {
        keyv[s] = (s < k) ? uperm[s] : __int_as_float(0x7F800000);
        idx[s] = s;
    }
    for (int i = 1; i < KMAX; ++i) {
        float kv = keyv[i]; int id = idx[i]; int j = i - 1;
        while (j >= 0 && keyv[j] > kv) { keyv[j + 1] = keyv[j]; idx[j + 1] = idx[j]; --j; }
        keyv[j + 1] = kv; idx[j + 1] = id;
    }

    for (int s = 0; s < KMAX; ++s) {
        int row = b * KMAX + s;
        int src; float it = 0.0f;
        if (s >= k)          src = s;          // inactive: copy self
        else if (do_permute) src = idx[s];     // permuted copy
        else { src = -1; it = 1.0f / tauv[s]; } // temperature warp
        src_arr[row] = src;
        itau_arr[row] = it;
    }
}

// ------------- per-batch reductions over h_ans (H=4096) -------------
__global__ __launch_bounds__(256) void rowred_kernel(const float* __restrict__ hr,
                                                     const float* __restrict__ hc,
                                                     float* __restrict__ cosb,
                                                     float* __restrict__ depb) {
    int b = blockIdx.x;
    const float4* r4 = (const float4*)(hr + (size_t)b * HH);
    const float4* c4 = (const float4*)(hc + (size_t)b * HH);
    float srr = 0.f, scc = 0.f, sxc = 0.f, sdd = 0.f;
    for (int i = threadIdx.x; i < HH / 4; i += 256) {
        float4 r = r4[i], c = c4[i];
        srr += r.x * r.x + r.y * r.y + r.z * r.z + r.w * r.w;
        scc += c.x * c.x + c.y * c.y + c.z * c.z + c.w * c.w;
        sxc += r.x * c.x + r.y * c.y + r.z * c.z + r.w * c.w;
        float dx = r.x - c.x, dy = r.y - c.y, dz = r.z - c.z, dw = r.w - c.w;
        sdd += dx * dx + dy * dy + dz * dz + dw * dw;
    }
#pragma unroll
    for (int o = 32; o; o >>= 1) {
        srr += __shfl_down(srr, o, 64);
        scc += __shfl_down(scc, o, 64);
        sxc += __shfl_down(sxc, o, 64);
        sdd += __shfl_down(sdd, o, 64);
    }
    __shared__ float red[4][4];
    int w = threadIdx.x >> 6;
    if ((threadIdx.x & 63) == 0) { red[w][0] = srr; red[w][1] = scc; red[w][2] = sxc; red[w][3] = sdd; }
    __syncthreads();
    if (threadIdx.x == 0) {
        float t0 = 0.f, t1 = 0.f, t2 = 0.f, t3 = 0.f;
        for (int i = 0; i < 4; ++i) { t0 += red[i][0]; t1 += red[i][1]; t2 += red[i][2]; t3 += red[i][3]; }
        float nr = fmaxf(sqrtf(t0), 1e-12f);
        float nc = fmaxf(sqrtf(t1), 1e-12f);
        cosb[b] = t2 / (nr * nc);
        depb[b] = sqrtf(t3);
    }
}

// ------------- JS divergence + final scalars -------------
__global__ void finalize_kernel(const float* __restrict__ dlr, const float* __restrict__ dlc,
                                const float* __restrict__ cosb, const float* __restrict__ depb,
                                float* __restrict__ out) {
    int b = threadIdx.x;  // 64 threads = 1 wave
    float lr[DVV], lc[DVV];
    float mr = -1e30f, mc = -1e30f;
#pragma unroll
    for (int v = 0; v < DVV; ++v) {
        lr[v] = dlr[b * DVV + v]; lc[v] = dlc[b * DVV + v];
        mr = fmaxf(mr, lr[v]); mc = fmaxf(mc, lc[v]);
    }
    float sr = 0.f, sc = 0.f;
#pragma unroll
    for (int v = 0; v < DVV; ++v) {
        lr[v] = expf(lr[v] - mr); sr += lr[v];
        lc[v] = expf(lc[v] - mc); sc += lc[v];
    }
    float js = 0.f;
#pragma unroll
    for (int v = 0; v < DVV; ++v) {
        float p = fmaxf(lr[v] / sr, EPSF);
        float q = fmaxf(lc[v] / sc, EPSF);
        float m = 0.5f * (p + q);
        float lm = logf(m);
        js += 0.5f * (p * (logf(p) - lm) + q * (logf(q) - lm));
    }
    float cs = cosb[b], dp = depb[b];
#pragma unroll
    for (int o = 32; o; o >>= 1) {
        js += __shfl_down(js, o, 64);
        cs += __shfl_down(cs, o, 64);
        dp += __shfl_down(dp, o, 64);
    }
    if (b == 0) {
        out[0] = logf(2.0f) - js * (1.0f / 64.0f);
        out[1] = cs * (1.0f / 64.0f) - 1.0f;
        out[2] = dp * (1.0f / 64.0f);
    }
}

// ------------- main: build p_cf_z (one block per row) -------------
// out points at d_out+3 (row base ≡ 12B mod 16 -> scalar dword accesses, unit-stride coalesced)
__global__ __launch_bounds__(1024) void cf_main_kernel(const float* __restrict__ p_z,
                                                       const int* __restrict__ src_arr,
                                                       const float* __restrict__ itau_arr,
                                                       float* __restrict__ out) {
    const int row = blockIdx.x;
    const int b = row >> 4;
    const int src = src_arr[row];
    float* dst = out + (size_t)row * VV;

    if (src >= 0) {  // copy (self or permuted slot)
        const float* s = p_z + ((size_t)((b << 4) + src)) * VV;
        for (int i = threadIdx.x; i < VV; i += 1024)
            dst[i] = s[i];
        return;
    }

    // temperature warp: p^(1/tau) / sum(p^(1/tau))
    const float it = itau_arr[row];
    const float* s = p_z + (size_t)row * VV;
    float v[32];
    float lsum = 0.f;
#pragma unroll
    for (int j = 0; j < 32; ++j) {
        int i = threadIdx.x + (j << 10);
        float val = 0.f;
        if (i < VV) {
            float p = fmaxf(s[i], EPSF);
            val = exp2f(__log2f(p) * it);
        }
        v[j] = val;
        lsum += val;
    }
    // block reduce (16 waves)
    __shared__ float red[16];
    float t = lsum;
#pragma unroll
    for (int o = 32; o; o >>= 1) t += __shfl_down(t, o, 64);
    if ((threadIdx.x & 63) == 0) red[threadIdx.x >> 6] = t;
    __syncthreads();
    if (threadIdx.x < 64) {
        float u = (threadIdx.x < 16) ? red[threadIdx.x] : 0.0f;
#pragma unroll
        for (int o = 8; o; o >>= 1) u += __shfl_down(u, o, 64);
        if (threadIdx.x == 0) red[0] = u;
    }
    __syncthreads();
    const float scale = 1.0f / red[0];
#pragma unroll
    for (int j = 0; j < 32; ++j) {
        int i = threadIdx.x + (j << 10);
        if (i < VV) dst[i] = v[j] * scale;
    }
}

extern "C" void kernel_launch(void* const* d_in, const int* in_sizes, int n_in,
                              void* d_out, int out_size, void* d_ws, size_t ws_size,
                              hipStream_t stream) {
    const float* p_z = (const float*)d_in[0];
    const float* dlr = (const float*)d_in[1];
    const float* dlc = (const float*)d_in[2];
    const float* hr  = (const float*)d_in[3];
    const float* hc  = (const float*)d_in[4];
    const int*   kv  = (const int*)d_in[5];
    float* out = (float*)d_out;

    int*   src_arr  = (int*)d_ws;
    float* itau_arr = (float*)d_ws + NROWS;
    float* cosb     = (float*)d_ws + 2 * NROWS;
    float* depb     = cosb + NB;

    setup_kernel<<<1, 64, 0, stream>>>(kv, src_arr, itau_arr);
    rowred_kernel<<<NB, 256, 0, stream>>>(hr, hc, cosb, depb);
    finalize_kernel<<<1, 64, 0, stream>>>(dlr, dlc, cosb, depb, out);
    cf_main_kernel<<<NROWS, 1024, 0, stream>>>(p_z, src_arr, itau_arr, out + 3);
}

// Round 2
// 62.636 us; speedup vs baseline: 1.4229x; 1.4229x over previous
//
#include <hip/hip_runtime.h>
#include <stdint.h>

#define NB    64       // batch
#define KMAX  16
#define VV    32000    // vocab
#define DVV   10
#define HH    4096
#define NROWS (NB*KMAX)
#define EPSF  1e-8f
#define NQ    8000     // float4 groups per row (4*8000 = 32000)

// ---------------- Threefry-2x32 (exact JAX reference implementation) ----------------
__device__ __forceinline__ uint32_t rotl32(uint32_t v, int r) { return (v << r) | (v >> (32 - r)); }

__device__ __forceinline__ void tf2x32(uint32_t k0, uint32_t k1, uint32_t c0, uint32_t c1,
                                       uint32_t& o0, uint32_t& o1) {
    uint32_t ks2 = k0 ^ k1 ^ 0x1BD11BDAu;
    uint32_t x0 = c0 + k0, x1 = c1 + k1;
    const int RA[4] = {13, 15, 26, 6};
    const int RB[4] = {17, 29, 16, 24};
#pragma unroll
    for (int i = 0; i < 4; ++i) { x0 += x1; x1 = rotl32(x1, RA[i]); x1 ^= x0; }
    x0 += k1; x1 += ks2 + 1u;
#pragma unroll
    for (int i = 0; i < 4; ++i) { x0 += x1; x1 = rotl32(x1, RB[i]); x1 ^= x0; }
    x0 += ks2; x1 += k0 + 2u;
#pragma unroll
    for (int i = 0; i < 4; ++i) { x0 += x1; x1 = rotl32(x1, RA[i]); x1 ^= x0; }
    x0 += k0; x1 += k1 + 3u;
#pragma unroll
    for (int i = 0; i < 4; ++i) { x0 += x1; x1 = rotl32(x1, RB[i]); x1 ^= x0; }
    x0 += k1; x1 += ks2 + 4u;
#pragma unroll
    for (int i = 0; i < 4; ++i) { x0 += x1; x1 = rotl32(x1, RA[i]); x1 ^= x0; }
    x0 += ks2; x1 += k0 + 5u;
    o0 = x0; o1 = x1;
}

__device__ __forceinline__ float bits_to_u01(uint32_t bits) {
    uint32_t fb = (bits >> 9) | 0x3F800000u;
    return __uint_as_float(fb) - 1.0f;
}

// ------------- setup: reproduce JAX randoms, build per-row descriptors -------------
// One thread per (b,s). Rank-scatter replaces the argsort: thread (b,t)'s stable
// rank r among its batch's keys (inactive -> +inf, ties by index) satisfies
// r==t for inactive slots, so scatter src[b*16+r]=t covers the whole table.
__global__ __launch_bounds__(1024) void setup_kernel(const int* __restrict__ k_vals,
                                                     int* __restrict__ src_arr,
                                                     float* __restrict__ itau_arr) {
    const int j = threadIdx.x;           // 0..1023
    const int b = j >> 4, s = j & 15;

    __shared__ float su[NROWS];
    __shared__ int   sk[NB];
    __shared__ int   sdp[NB];

    // split(key(0), 3): counts=[0..5]; out=[a0,a1,a2,b0,b1,b2] -> (3,2)
    uint32_t a0, b0, a1, b1, a2, b2;
    tf2x32(0u, 0u, 0u, 3u, a0, b0);
    tf2x32(0u, 0u, 1u, 4u, a1, b1);
    tf2x32(0u, 0u, 2u, 5u, a2, b2);
    const uint32_t kdec0 = a0, kdec1 = a1;
    const uint32_t kperm0 = a2, kperm1 = b0;
    const uint32_t ktau0 = b1, ktau1 = b2;

    // u_perm[j], tau[j]: size-1024 draws, counts split [0..511],[512..1023]
    uint32_t y0, y1, pb, tb;
    if (j < 512) { tf2x32(kperm0, kperm1, (uint32_t)j, (uint32_t)(j + 512), y0, y1); pb = y0; }
    else         { tf2x32(kperm0, kperm1, (uint32_t)(j - 512), (uint32_t)j, y0, y1); pb = y1; }
    su[j] = bits_to_u01(pb);
    if (j < 512) { tf2x32(ktau0, ktau1, (uint32_t)j, (uint32_t)(j + 512), y0, y1); tb = y0; }
    else         { tf2x32(ktau0, ktau1, (uint32_t)(j - 512), (uint32_t)j, y0, y1); tb = y1; }
    float tau = fmaxf(0.7f, bits_to_u01(tb) * 0.9f + 0.7f);
    float itau = 1.0f / tau;

    if (j < NB) {
        uint32_t bits;
        if (j < 32) { tf2x32(kdec0, kdec1, (uint32_t)j, (uint32_t)(j + 32), y0, y1); bits = y0; }
        else        { tf2x32(kdec0, kdec1, (uint32_t)(j - 32), (uint32_t)j, y0, y1); bits = y1; }
        float u_dec = bits_to_u01(bits);
        int k = k_vals[j];
        float prob = (k >= 2) ? 0.5f : 0.0f;
        sk[j] = k;
        sdp[j] = (k > 1) && (u_dec < prob);
    }
    __syncthreads();

    const int k = sk[b];
    const bool dp = sdp[b] != 0;
    const float INF = __int_as_float(0x7F800000);
    const float myk = (s < k) ? su[j] : INF;

    int r = 0;
#pragma unroll
    for (int t = 0; t < KMAX; ++t) {
        float kt = (t < k) ? su[(b << 4) + t] : INF;
        r += (kt < myk) || (kt == myk && t < s);
    }

    if (s >= k)      { src_arr[j] = s;            itau_arr[j] = 0.0f; }
    else if (dp)     { src_arr[(b << 4) + r] = s; itau_arr[(b << 4) + r] = 0.0f; }
    else             { src_arr[j] = -1;           itau_arr[j] = itau; }
}

// ------------- per-batch reductions over h_ans (H=4096) -------------
__global__ __launch_bounds__(256) void rowred_kernel(const float* __restrict__ hr,
                                                     const float* __restrict__ hc,
                                                     float* __restrict__ cosb,
                                                     float* __restrict__ depb) {
    int b = blockIdx.x;
    const float4* r4 = (const float4*)(hr + (size_t)b * HH);
    const float4* c4 = (const float4*)(hc + (size_t)b * HH);
    float srr = 0.f, scc = 0.f, sxc = 0.f, sdd = 0.f;
    for (int i = threadIdx.x; i < HH / 4; i += 256) {
        float4 r = r4[i], c = c4[i];
        srr += r.x * r.x + r.y * r.y + r.z * r.z + r.w * r.w;
        scc += c.x * c.x + c.y * c.y + c.z * c.z + c.w * c.w;
        sxc += r.x * c.x + r.y * c.y + r.z * c.z + r.w * c.w;
        float dx = r.x - c.x, dy = r.y - c.y, dz = r.z - c.z, dw = r.w - c.w;
        sdd += dx * dx + dy * dy + dz * dz + dw * dw;
    }
#pragma unroll
    for (int o = 32; o; o >>= 1) {
        srr += __shfl_down(srr, o, 64);
        scc += __shfl_down(scc, o, 64);
        sxc += __shfl_down(sxc, o, 64);
        sdd += __shfl_down(sdd, o, 64);
    }
    __shared__ float red[4][4];
    int w = threadIdx.x >> 6;
    if ((threadIdx.x & 63) == 0) { red[w][0] = srr; red[w][1] = scc; red[w][2] = sxc; red[w][3] = sdd; }
    __syncthreads();
    if (threadIdx.x == 0) {
        float t0 = 0.f, t1 = 0.f, t2 = 0.f, t3 = 0.f;
        for (int i = 0; i < 4; ++i) { t0 += red[i][0]; t1 += red[i][1]; t2 += red[i][2]; t3 += red[i][3]; }
        float nr = fmaxf(sqrtf(t0), 1e-12f);
        float nc = fmaxf(sqrtf(t1), 1e-12f);
        cosb[b] = t2 / (nr * nc);
        depb[b] = sqrtf(t3);
    }
}

// ------------- JS divergence + final scalars -------------
__global__ void finalize_kernel(const float* __restrict__ dlr, const float* __restrict__ dlc,
                                const float* __restrict__ cosb, const float* __restrict__ depb,
                                float* __restrict__ out) {
    int b = threadIdx.x;  // 64 threads = 1 wave
    float lr[DVV], lc[DVV];
    float mr = -1e30f, mc = -1e30f;
#pragma unroll
    for (int v = 0; v < DVV; ++v) {
        lr[v] = dlr[b * DVV + v]; lc[v] = dlc[b * DVV + v];
        mr = fmaxf(mr, lr[v]); mc = fmaxf(mc, lc[v]);
    }
    float sr = 0.f, sc = 0.f;
#pragma unroll
    for (int v = 0; v < DVV; ++v) {
        lr[v] = expf(lr[v] - mr); sr += lr[v];
        lc[v] = expf(lc[v] - mc); sc += lc[v];
    }
    float js = 0.f;
#pragma unroll
    for (int v = 0; v < DVV; ++v) {
        float p = fmaxf(lr[v] / sr, EPSF);
        float q = fmaxf(lc[v] / sc, EPSF);
        float m = 0.5f * (p + q);
        float lm = logf(m);
        js += 0.5f * (p * (logf(p) - lm) + q * (logf(q) - lm));
    }
    float cs = cosb[b], dp = depb[b];
#pragma unroll
    for (int o = 32; o; o >>= 1) {
        js += __shfl_down(js, o, 64);
        cs += __shfl_down(cs, o, 64);
        dp += __shfl_down(dp, o, 64);
    }
    if (b == 0) {
        out[0] = logf(2.0f) - js * (1.0f / 64.0f);
        out[1] = cs * (1.0f / 64.0f) - 1.0f;
        out[2] = dp * (1.0f / 64.0f);
    }
}

// ------------- main: build p_cf_z (one block per row) -------------
// dst row base is at float-offset 3+row*32000 (== 3 mod 4). Loads are aligned
// float4 at src element 4q; stores are realigned float4 at dst element 4q+1:
// st = (my.y, my.z, my.w, nextlane.x) via __shfl_down; lane-63 / row-tail scalar.
__global__ __launch_bounds__(1024) void cf_main_kernel(const float* __restrict__ p_z,
                                                       const int* __restrict__ src_arr,
                                                       const float* __restrict__ itau_arr,
                                                       float* __restrict__ out) {
    const int row = blockIdx.x;
    const int b = row >> 4;
    const int src = src_arr[row];
    const int tid = threadIdx.x;
    const int lane = tid & 63;
    float* dst = out + (size_t)row * VV;

    if (src >= 0) {  // copy (self or permuted slot)
        const float* s = p_z + ((size_t)((b << 4) + src)) * VV;
#pragma unroll
        for (int i = 0; i < 8; ++i) {
            const int q = tid + (i << 10);
            if (q >= NQ) break;                 // whole waves drop out together
            float4 v = *(const float4*)(s + (q << 2));
            float nx = __shfl_down(v.x, 1, 64);
            if (q < NQ - 1) {
                float4 st;
                st.x = v.y; st.y = v.z; st.z = v.w;
                st.w = (lane == 63) ? s[(q << 2) + 4] : nx;
                *(float4*)(dst + (q << 2) + 1) = st;
            }
            if (q == 0) dst[0] = v.x;
            if (q == NQ - 1) { dst[VV - 3] = v.y; dst[VV - 2] = v.z; dst[VV - 1] = v.w; }
        }
        return;
    }

    // temperature warp: p^(1/tau) / sum(p^(1/tau)), row cached in 8 float4 regs
    const float it = itau_arr[row];
    const float* s = p_z + (size_t)row * VV;
    float4 r[8];
    float lsum = 0.f;
#pragma unroll
    for (int i = 0; i < 8; ++i) {
        const int q = tid + (i << 10);
        if (q < NQ) {
            float4 v = *(const float4*)(s + (q << 2));
            v.x = exp2f(__log2f(fmaxf(v.x, EPSF)) * it);
            v.y = exp2f(__log2f(fmaxf(v.y, EPSF)) * it);
            v.z = exp2f(__log2f(fmaxf(v.z, EPSF)) * it);
            v.w = exp2f(__log2f(fmaxf(v.w, EPSF)) * it);
            r[i] = v;
            lsum += v.x + v.y + v.z + v.w;
        } else {
            r[i] = make_float4(0.f, 0.f, 0.f, 0.f);
        }
    }
    // block reduce (16 waves)
    __shared__ float red[16];
    float t = lsum;
#pragma unroll
    for (int o = 32; o; o >>= 1) t += __shfl_down(t, o, 64);
    if (lane == 0) red[tid >> 6] = t;
    __syncthreads();
    if (tid < 64) {
        float u = (tid < 16) ? red[tid] : 0.0f;
#pragma unroll
        for (int o = 8; o; o >>= 1) u += __shfl_down(u, o, 64);
        if (tid == 0) red[0] = u;
    }
    __syncthreads();
    const float scale = 1.0f / red[0];

#pragma unroll
    for (int i = 0; i < 8; ++i) {
        const int q = tid + (i << 10);
        if (q >= NQ) break;                     // whole waves drop out together
        float nx = __shfl_down(r[i].x, 1, 64);
        if (q < NQ - 1) {
            float4 st;
            st.x = r[i].y * scale; st.y = r[i].z * scale; st.z = r[i].w * scale;
            if (lane == 63)
                nx = exp2f(__log2f(fmaxf(s[(q << 2) + 4], EPSF)) * it);
            st.w = nx * scale;
            *(float4*)(dst + (q << 2) + 1) = st;
        }
        if (q == 0) dst[0] = r[i].x * scale;
        if (q == NQ - 1) {
            dst[VV - 3] = r[i].y * scale;
            dst[VV - 2] = r[i].z * scale;
            dst[VV - 1] = r[i].w * scale;
        }
    }
}

extern "C" void kernel_launch(void* const* d_in, const int* in_sizes, int n_in,
                              void* d_out, int out_size, void* d_ws, size_t ws_size,
                              hipStream_t stream) {
    const float* p_z = (const float*)d_in[0];
    const float* dlr = (const float*)d_in[1];
    const float* dlc = (const float*)d_in[2];
    const float* hr  = (const float*)d_in[3];
    const float* hc  = (const float*)d_in[4];
    const int*   kv  = (const int*)d_in[5];
    float* out = (float*)d_out;

    int*   src_arr  = (int*)d_ws;
    float* itau_arr = (float*)d_ws + NROWS;
    float* cosb     = (float*)d_ws + 2 * NROWS;
    float* depb     = cosb + NB;

    setup_kernel<<<1, 1024, 0, stream>>>(kv, src_arr, itau_arr);
    cf_main_kernel<<<NROWS, 1024, 0, stream>>>(p_z, src_arr, itau_arr, out + 3);
    rowred_kernel<<<NB, 256, 0, stream>>>(hr, hc, cosb, depb);
    finalize_kernel<<<1, 64, 0, stream>>>(dlr, dlc, cosb, depb, out);
}

// Round 4
// 57.535 us; speedup vs baseline: 1.5491x; 1.0887x over previous
//
#include <hip/hip_runtime.h>
#include <stdint.h>

#define NB    64       // batch
#define KMAX  16
#define VV    32000    // vocab
#define DVV   10
#define HH    4096
#define NROWS (NB*KMAX)
#define EPSF  1e-8f
#define NQ    8000     // float4 groups per row (4*8000 = 32000)

typedef float floatx4 __attribute__((ext_vector_type(4)));

// ---------------- Threefry-2x32 (exact JAX reference implementation) ----------------
__device__ __forceinline__ uint32_t rotl32(uint32_t v, int r) { return (v << r) | (v >> (32 - r)); }

__device__ __forceinline__ void tf2x32(uint32_t k0, uint32_t k1, uint32_t c0, uint32_t c1,
                                       uint32_t& o0, uint32_t& o1) {
    uint32_t ks2 = k0 ^ k1 ^ 0x1BD11BDAu;
    uint32_t x0 = c0 + k0, x1 = c1 + k1;
    const int RA[4] = {13, 15, 26, 6};
    const int RB[4] = {17, 29, 16, 24};
#pragma unroll
    for (int i = 0; i < 4; ++i) { x0 += x1; x1 = rotl32(x1, RA[i]); x1 ^= x0; }
    x0 += k1; x1 += ks2 + 1u;
#pragma unroll
    for (int i = 0; i < 4; ++i) { x0 += x1; x1 = rotl32(x1, RB[i]); x1 ^= x0; }
    x0 += ks2; x1 += k0 + 2u;
#pragma unroll
    for (int i = 0; i < 4; ++i) { x0 += x1; x1 = rotl32(x1, RA[i]); x1 ^= x0; }
    x0 += k0; x1 += k1 + 3u;
#pragma unroll
    for (int i = 0; i < 4; ++i) { x0 += x1; x1 = rotl32(x1, RB[i]); x1 ^= x0; }
    x0 += k1; x1 += ks2 + 4u;
#pragma unroll
    for (int i = 0; i < 4; ++i) { x0 += x1; x1 = rotl32(x1, RA[i]); x1 ^= x0; }
    x0 += ks2; x1 += k0 + 5u;
    o0 = x0; o1 = x1;
}

__device__ __forceinline__ float bits_to_u01(uint32_t bits) {
    uint32_t fb = (bits >> 9) | 0x3F800000u;
    return __uint_as_float(fb) - 1.0f;
}

__device__ __forceinline__ void nt_store4(float* p, float a, float b, float c, float d) {
    floatx4 v = {a, b, c, d};
    __builtin_nontemporal_store(v, (floatx4*)p);
}

// ------------- setup: reproduce JAX randoms, build per-row descriptors -------------
__global__ __launch_bounds__(1024) void setup_kernel(const int* __restrict__ k_vals,
                                                     int* __restrict__ src_arr,
                                                     float* __restrict__ itau_arr) {
    const int j = threadIdx.x;           // 0..1023
    const int b = j >> 4, s = j & 15;

    __shared__ float su[NROWS];
    __shared__ int   sk[NB];
    __shared__ int   sdp[NB];

    // split(key(0), 3): counts=[0..5]; out=[a0,a1,a2,b0,b1,b2] -> (3,2)
    uint32_t a0, b0, a1, b1, a2, b2;
    tf2x32(0u, 0u, 0u, 3u, a0, b0);
    tf2x32(0u, 0u, 1u, 4u, a1, b1);
    tf2x32(0u, 0u, 2u, 5u, a2, b2);
    const uint32_t kdec0 = a0, kdec1 = a1;
    const uint32_t kperm0 = a2, kperm1 = b0;
    const uint32_t ktau0 = b1, ktau1 = b2;

    // u_perm[j], tau[j]: size-1024 draws, counts split [0..511],[512..1023]
    uint32_t y0, y1, pb, tb;
    if (j < 512) { tf2x32(kperm0, kperm1, (uint32_t)j, (uint32_t)(j + 512), y0, y1); pb = y0; }
    else         { tf2x32(kperm0, kperm1, (uint32_t)(j - 512), (uint32_t)j, y0, y1); pb = y1; }
    su[j] = bits_to_u01(pb);
    if (j < 512) { tf2x32(ktau0, ktau1, (uint32_t)j, (uint32_t)(j + 512), y0, y1); tb = y0; }
    else         { tf2x32(ktau0, ktau1, (uint32_t)(j - 512), (uint32_t)j, y0, y1); tb = y1; }
    float tau = fmaxf(0.7f, bits_to_u01(tb) * 0.9f + 0.7f);
    float itau = 1.0f / tau;

    if (j < NB) {
        uint32_t bits;
        if (j < 32) { tf2x32(kdec0, kdec1, (uint32_t)j, (uint32_t)(j + 32), y0, y1); bits = y0; }
        else        { tf2x32(kdec0, kdec1, (uint32_t)(j - 32), (uint32_t)j, y0, y1); bits = y1; }
        float u_dec = bits_to_u01(bits);
        int k = k_vals[j];
        float prob = (k >= 2) ? 0.5f : 0.0f;
        sk[j] = k;
        sdp[j] = (k > 1) && (u_dec < prob);
    }
    __syncthreads();

    const int k = sk[b];
    const bool dp = sdp[b] != 0;
    const float INF = __int_as_float(0x7F800000);
    const float myk = (s < k) ? su[j] : INF;

    int r = 0;
#pragma unroll
    for (int t = 0; t < KMAX; ++t) {
        float kt = (t < k) ? su[(b << 4) + t] : INF;
        r += (kt < myk) || (kt == myk && t < s);
    }

    if (s >= k)      { src_arr[j] = s;            itau_arr[j] = 0.0f; }
    else if (dp)     { src_arr[(b << 4) + r] = s; itau_arr[(b << 4) + r] = 0.0f; }
    else             { src_arr[j] = -1;           itau_arr[j] = itau; }
}

// ------------- per-batch reductions over h_ans (H=4096) -------------
__global__ __launch_bounds__(256) void rowred_kernel(const float* __restrict__ hr,
                                                     const float* __restrict__ hc,
                                                     float* __restrict__ cosb,
                                                     float* __restrict__ depb) {
    int b = blockIdx.x;
    const float4* r4 = (const float4*)(hr + (size_t)b * HH);
    const float4* c4 = (const float4*)(hc + (size_t)b * HH);
    float srr = 0.f, scc = 0.f, sxc = 0.f, sdd = 0.f;
    for (int i = threadIdx.x; i < HH / 4; i += 256) {
        float4 r = r4[i], c = c4[i];
        srr += r.x * r.x + r.y * r.y + r.z * r.z + r.w * r.w;
        scc += c.x * c.x + c.y * c.y + c.z * c.z + c.w * c.w;
        sxc += r.x * c.x + r.y * c.y + r.z * c.z + r.w * c.w;
        float dx = r.x - c.x, dy = r.y - c.y, dz = r.z - c.z, dw = r.w - c.w;
        sdd += dx * dx + dy * dy + dz * dz + dw * dw;
    }
#pragma unroll
    for (int o = 32; o; o >>= 1) {
        srr += __shfl_down(srr, o, 64);
        scc += __shfl_down(scc, o, 64);
        sxc += __shfl_down(sxc, o, 64);
        sdd += __shfl_down(sdd, o, 64);
    }
    __shared__ float red[4][4];
    int w = threadIdx.x >> 6;
    if ((threadIdx.x & 63) == 0) { red[w][0] = srr; red[w][1] = scc; red[w][2] = sxc; red[w][3] = sdd; }
    __syncthreads();
    if (threadIdx.x == 0) {
        float t0 = 0.f, t1 = 0.f, t2 = 0.f, t3 = 0.f;
        for (int i = 0; i < 4; ++i) { t0 += red[i][0]; t1 += red[i][1]; t2 += red[i][2]; t3 += red[i][3]; }
        float nr = fmaxf(sqrtf(t0), 1e-12f);
        float nc = fmaxf(sqrtf(t1), 1e-12f);
        cosb[b] = t2 / (nr * nc);
        depb[b] = sqrtf(t3);
    }
}

// ------------- JS divergence + final scalars -------------
__global__ void finalize_kernel(const float* __restrict__ dlr, const float* __restrict__ dlc,
                                const float* __restrict__ cosb, const float* __restrict__ depb,
                                float* __restrict__ out) {
    int b = threadIdx.x;  // 64 threads = 1 wave
    float lr[DVV], lc[DVV];
    float mr = -1e30f, mc = -1e30f;
#pragma unroll
    for (int v = 0; v < DVV; ++v) {
        lr[v] = dlr[b * DVV + v]; lc[v] = dlc[b * DVV + v];
        mr = fmaxf(mr, lr[v]); mc = fmaxf(mc, lc[v]);
    }
    float sr = 0.f, sc = 0.f;
#pragma unroll
    for (int v = 0; v < DVV; ++v) {
        lr[v] = expf(lr[v] - mr); sr += lr[v];
        lc[v] = expf(lc[v] - mc); sc += lc[v];
    }
    float js = 0.f;
#pragma unroll
    for (int v = 0; v < DVV; ++v) {
        float p = fmaxf(lr[v] / sr, EPSF);
        float q = fmaxf(lc[v] / sc, EPSF);
        float m = 0.5f * (p + q);
        float lm = logf(m);
        js += 0.5f * (p * (logf(p) - lm) + q * (logf(q) - lm));
    }
    float cs = cosb[b], dp = depb[b];
#pragma unroll
    for (int o = 32; o; o >>= 1) {
        js += __shfl_down(js, o, 64);
        cs += __shfl_down(cs, o, 64);
        dp += __shfl_down(dp, o, 64);
    }
    if (b == 0) {
        out[0] = logf(2.0f) - js * (1.0f / 64.0f);
        out[1] = cs * (1.0f / 64.0f) - 1.0f;
        out[2] = dp * (1.0f / 64.0f);
    }
}

// ------------- main: build p_cf_z (one block per row) -------------
// dst row base ≡ 3 mod 4 floats. Thread handles OUT elems 4q+1..4q+4: the
// STORE at dst+4q+1 is 16B-aligned; the LOAD of the same span is a
// dword-aligned (legal) unaligned float4. No shuffles, no masked edge loads —
// edges (elem 0, last 3 elems) are done once by threads 0/1. NT stores keep
// the write stream from evicting p_z out of L3.
__global__ __launch_bounds__(1024) void cf_main_kernel(const float* __restrict__ p_z,
                                                       const int* __restrict__ src_arr,
                                                       const float* __restrict__ itau_arr,
                                                       float* __restrict__ out) {
    const int row = blockIdx.x;
    const int b = row >> 4;
    const int src = src_arr[row];
    const int tid = threadIdx.x;
    float* dst = out + (size_t)row * VV;

    if (src >= 0) {  // copy (self or permuted slot)
        const float* s = p_z + ((size_t)((b << 4) + src)) * VV;
#pragma unroll
        for (int i = 0; i < 8; ++i) {
            const int q = tid + (i << 10);
            if (q < NQ - 1) {
                float4 v = *(const float4*)(s + (q << 2) + 1);
                nt_store4(dst + (q << 2) + 1, v.x, v.y, v.z, v.w);
            }
        }
        if (tid == 0) dst[0] = s[0];
        if (tid == 1) {
            dst[VV - 3] = s[VV - 3];
            dst[VV - 2] = s[VV - 2];
            dst[VV - 1] = s[VV - 1];
        }
        return;
    }

    // temperature warp: p^(1/tau) / sum(p^(1/tau)); each thread caches the
    // exact spans it will store (unaligned loads, aligned stores).
    const float it = itau_arr[row];
    const float* s = p_z + (size_t)row * VV;
    float4 r[8];
    float e0 = 0.f, t0 = 0.f, t1 = 0.f, t2 = 0.f;
    float lsum = 0.f;
#pragma unroll
    for (int i = 0; i < 8; ++i) {
        const int q = tid + (i << 10);
        if (q < NQ - 1) {
            float4 v = *(const float4*)(s + (q << 2) + 1);
            v.x = exp2f(__log2f(fmaxf(v.x, EPSF)) * it);
            v.y = exp2f(__log2f(fmaxf(v.y, EPSF)) * it);
            v.z = exp2f(__log2f(fmaxf(v.z, EPSF)) * it);
            v.w = exp2f(__log2f(fmaxf(v.w, EPSF)) * it);
            r[i] = v;
            lsum += v.x + v.y + v.z + v.w;
        } else {
            r[i] = make_float4(0.f, 0.f, 0.f, 0.f);
        }
    }
    if (tid == 0) { e0 = exp2f(__log2f(fmaxf(s[0], EPSF)) * it); lsum += e0; }
    if (tid == 1) {
        t0 = exp2f(__log2f(fmaxf(s[VV - 3], EPSF)) * it);
        t1 = exp2f(__log2f(fmaxf(s[VV - 2], EPSF)) * it);
        t2 = exp2f(__log2f(fmaxf(s[VV - 1], EPSF)) * it);
        lsum += t0 + t1 + t2;
    }
    // block reduce (16 waves)
    __shared__ float red[16];
    float t = lsum;
#pragma unroll
    for (int o = 32; o; o >>= 1) t += __shfl_down(t, o, 64);
    if ((tid & 63) == 0) red[tid >> 6] = t;
    __syncthreads();
    if (tid < 64) {
        float u = (tid < 16) ? red[tid] : 0.0f;
#pragma unroll
        for (int o = 8; o; o >>= 1) u += __shfl_down(u, o, 64);
        if (tid == 0) red[0] = u;
    }
    __syncthreads();
    const float scale = 1.0f / red[0];

#pragma unroll
    for (int i = 0; i < 8; ++i) {
        const int q = tid + (i << 10);
        if (q < NQ - 1) {
            nt_store4(dst + (q << 2) + 1,
                      r[i].x * scale, r[i].y * scale, r[i].z * scale, r[i].w * scale);
        }
    }
    if (tid == 0) dst[0] = e0 * scale;
    if (tid == 1) {
        dst[VV - 3] = t0 * scale;
        dst[VV - 2] = t1 * scale;
        dst[VV - 1] = t2 * scale;
    }
}

extern "C" void kernel_launch(void* const* d_in, const int* in_sizes, int n_in,
                              void* d_out, int out_size, void* d_ws, size_t ws_size,
                              hipStream_t stream) {
    const float* p_z = (const float*)d_in[0];
    const float* dlr = (const float*)d_in[1];
    const float* dlc = (const float*)d_in[2];
    const float* hr  = (const float*)d_in[3];
    const float* hc  = (const float*)d_in[4];
    const int*   kv  = (const int*)d_in[5];
    float* out = (float*)d_out;

    int*   src_arr  = (int*)d_ws;
    float* itau_arr = (float*)d_ws + NROWS;
    float* cosb     = (float*)d_ws + 2 * NROWS;
    float* depb     = cosb + NB;

    setup_kernel<<<1, 1024, 0, stream>>>(kv, src_arr, itau_arr);
    cf_main_kernel<<<NROWS, 1024, 0, stream>>>(p_z, src_arr, itau_arr, out + 3);
    rowred_kernel<<<NB, 256, 0, stream>>>(hr, hc, cosb, depb);
    finalize_kernel<<<1, 64, 0, stream>>>(dlr, dlc, cosb, depb, out);
}